// Round 13
// baseline (626.971 us; speedup 1.0000x reference)
//
#include <hip/hip_runtime.h>
#include <cstdint>
#include <cstddef>

#define T_STEPS 1024
#define NBLK    256   // 512 batch / 2 per block; 1 block per CU
#define LOG2E   1.4426950408889634f

typedef __attribute__((ext_vector_type(8))) _Float16 half8;
typedef __attribute__((ext_vector_type(4))) _Float16 half4;
typedef __attribute__((ext_vector_type(4))) float    f32x4;

static __device__ __forceinline__ float fexp2(float x) {
#if defined(__has_builtin) && __has_builtin(__builtin_amdgcn_exp2f)
  return __builtin_amdgcn_exp2f(x);
#else
  return __exp2f(x);
#endif
}
// pre-acts arrive PRE-SCALED by log2e (weights/bias scaled at load)
static __device__ __forceinline__ float sigm2(float a) {          // sigmoid(a/log2e)
  return __builtin_amdgcn_rcpf(1.0f + fexp2(-a));
}
static __device__ __forceinline__ float tanhg2(float a) {         // tanh(a/log2e)
  return 2.0f * __builtin_amdgcn_rcpf(1.0f + fexp2(-(a + a))) - 1.0f;
}
static __device__ __forceinline__ float tanhc(float c) {          // tanh(c), c unscaled
  return 1.0f - 2.0f * __builtin_amdgcn_rcpf(1.0f + fexp2(c * (2.0f * LOG2E)));
}

static __device__ __forceinline__ half8 load8s(const float* s, float sc) {
  float4 a = ((const float4*)s)[0];
  float4 b = ((const float4*)s)[1];
  half8 h;
  h[0] = (_Float16)(a.x * sc); h[1] = (_Float16)(a.y * sc);
  h[2] = (_Float16)(a.z * sc); h[3] = (_Float16)(a.w * sc);
  h[4] = (_Float16)(b.x * sc); h[5] = (_Float16)(b.y * sc);
  h[6] = (_Float16)(b.z * sc); h[7] = (_Float16)(b.w * sc);
  return h;
}
static __device__ __forceinline__ half4 cvt4(float4 v) {
  half4 h; h[0] = (_Float16)v.x; h[1] = (_Float16)v.y; h[2] = (_Float16)v.z; h[3] = (_Float16)v.w;
  return h;
}
static __device__ __forceinline__ f32x4 splat4(float v) { return (f32x4){v, v, v, v}; }

// lgkm-only workgroup barrier: drains LDS ops (producer->consumer visibility)
// but leaves global loads in flight across the barrier.
static __device__ __forceinline__ void barrier_lds() {
  __asm__ volatile("s_waitcnt lgkmcnt(0)\n\ts_barrier" ::: "memory");
}

// R13 = R12 with the partial-buffer indexing bug fixed: G buffers now carry a
// wq dimension — [par][wq][bm][col][tile] — so the 4 mid waves (different
// 16-unit groups) no longer collide. (R12 failed absmax 0.54: all wq wrote to
// the same [bm][col][tile] slots.)
//
// 12-wave producer/consumer K-split (3 waves/SIMD):
//  waves 0-3  "post-L1": read h1 frags + Gx partial (bias+x-proj inside) ->
//             8 MFMA -> acts -> write h1_p.
//  waves 4-7  "post-L2": read h2 frags + Gh1 partial -> 8 MFMA -> acts ->
//             write h2_{p-2} (skew 2, R11-verified).
//  waves 8-11 "mid": no acts. Gh1 partial for L2 step p-1 (h1_{p-1}, 8 MFMA,
//             bias2 C-init) and Gx partial for L1 step p+1 (x window, 4 MFMA,
//             bias1 C-init); dump D-reg0 rows (lanes 0-31) as one b128 each.
// Per SIMD: 28 MFMA (543-cyc issue floor unchanged) across 3 independent
// streams. ONE lgkm-only barrier per phase.
// hstate[buf][kstep][batch][32] bank-disjoint (R9-verified). Writes at phase
// p -> buf p&1, reads -> buf (p+1)&1; G parities: read p&1, write (p+1)&1.
// MFMA layouts (m89/m120-verified): A[m=l&15][k=(l>>4)*8+j];
// B[k=(l>>4)*8+j][n=l&15]; D[row=(l>>4)*4+reg][col=l&15]; batch at A-rows 0,4
// -> D reg0 = batch0 in lanes 0-15, batch1 in lanes 16-31.
__global__ __launch_bounds__(768, 3) void lstm_fused(
    const float* __restrict__ x,
    const float* __restrict__ w_ih1, const float* __restrict__ w_hh1,
    const float* __restrict__ b_ih1, const float* __restrict__ b_hh1,
    const float* __restrict__ w_ih2, const float* __restrict__ w_hh2,
    const float* __restrict__ b_ih2, const float* __restrict__ b_hh2,
    const float* __restrict__ fc1_w, const float* __restrict__ fc1_b,
    const float* __restrict__ fc2_w, const float* __restrict__ fc2_b,
    const float* __restrict__ ln_g, const float* __restrict__ ln_b,
    float* __restrict__ out)
{
  // ks0 = h1[0:32), ks1 = h1[32:64), ks2 = h2[0:32), ks3 = h2[32:64)
  __shared__ __align__(16) _Float16 hstate[2][4][2][32];     // 1 KB, bank-disjoint
  __shared__ __align__(16) _Float16 xbig[2][16][2][32];      // 4 KB
  __shared__ __align__(16) float Gx [2][4][2][16][4];        // 4 KB [par][wq][bm][col][tile]
  __shared__ __align__(16) float Gh1[2][4][2][16][4];        // 4 KB
  __shared__ __align__(16) float hfin[2][64];
  __shared__ __align__(16) float y1s[2][128];
  __shared__ __align__(16) float y2s[2][128];
  __shared__ float redmu[2], redrs[2];

  const int t   = threadIdx.x;
  const int b   = blockIdx.x;
  const int l   = t & 63;
  const int w   = t >> 6;       // wave 0..11
  const int wq  = w & 3;        // unit group
  const int col = l & 15;
  const int q   = l >> 4;       // quad
  const int bmA = ((l & 15) >> 2) & 1;  // batch of this lane's A-row

  const int role = (w < 4) ? 0 : (w < 8) ? 1 : 2;   // 0=postL1, 1=postL2, 2=mid

  // ---- init: zero h-state (both buffers: 512 halves) ----
  if (t < 512) ((_Float16*)hstate)[t] = (_Float16)0.0f;

  // ---- init: preload x[0..16) into xbig buf0 ----
  if (t < 256) {
    const int b0 = t >> 7, r0 = t & 127, tr0 = r0 >> 3, ii0 = r0 & 7;
    const float4 v = *(const float4*)(x + ((size_t)(2 * b + b0) * T_STEPS + tr0) * 32 + ii0 * 4);
    *(half4*)((char*)xbig + tr0 * 128 + b0 * 64 + ii0 * 8) = cvt4(v);
  }

  // ---- stationary weights (pre-scaled by log2e) ----
  half8 wbh[4][2];   // post-L1: w_hh1; post-L2: w_hh2; mid: w_ih2
  half8 wmx[4];      // mid: w_ih1 (x kstep)
  {
    const int ko = q * 8;
    #pragma unroll
    for (int tt = 0; tt < 4; ++tt) {
      const int r = tt * 64 + wq * 16 + col;
      if (role == 0) {
        wbh[tt][0] = load8s(w_hh1 + r * 64 + ko, LOG2E);
        wbh[tt][1] = load8s(w_hh1 + r * 64 + 32 + ko, LOG2E);
      } else if (role == 1) {
        wbh[tt][0] = load8s(w_hh2 + r * 64 + ko, LOG2E);
        wbh[tt][1] = load8s(w_hh2 + r * 64 + 32 + ko, LOG2E);
      } else {
        wbh[tt][0] = load8s(w_ih2 + r * 64 + ko, LOG2E);
        wbh[tt][1] = load8s(w_ih2 + r * 64 + 32 + ko, LOG2E);
        wmx[tt]    = load8s(w_ih1 + r * 32 + ko, LOG2E);
      }
    }
  }
  // mid biases (folded into partial C-init)
  float bia1[4], bia2[4];
  if (role == 2) {
    #pragma unroll
    for (int tt = 0; tt < 4; ++tt) {
      const int r = tt * 64 + wq * 16 + col;
      bia1[tt] = (b_ih1[r] + b_hh1[r]) * LOG2E;
      bia2[tt] = (b_ih2[r] + b_hh2[r]) * LOG2E;
    }
  }

  // act-lane mapping (post roles, lanes 0-31): unit u, batch = l>>4
  const int u   = wq * 16 + col;
  const int abm = l >> 4;
  const int hwofs = ((role == 1 ? 2 : 0) + (u >> 5)) * 128 + abm * 64 + (u & 31) * 2;

  // partial-buffer lane byte offsets (per-parity size 2048 B; wq stride 512 B)
  const int gprd = wq * 512 + (q & 1) * 256 + col * 16;        // read (q2,3 dup -> broadcast)
  const int gpwr = wq * 512 + (l >> 4) * 256 + (l & 15) * 16;  // write (lanes 0-31, b128)

  // x-prefetch lanes: lanes 32-63 of waves 0-7 (256 lanes)
  const bool isx = (w < 8) && (l >= 32);
  const int g   = w * 32 + (l - 32);
  const int xbm = g >> 7, xr = g & 127, xtr = xr >> 3, xii = xr & 7;
  const float* xsrc = x + ((size_t)(2 * b + xbm) * T_STEPS) * 32 + xii * 4;

  const char* hsbase = (const char*)hstate + bmA * 64 + q * 16;  // + buf*512 + ks*128
  const char* xwbase = (const char*)xbig   + bmA * 64 + q * 16;  // + buf*2048 + slot*128

  __syncthreads();

  // ---- precompute Gx partial for step 0 (parity 0) ----
  if (role == 2) {
    const half8 ax = *(const half8*)xwbase;   // buf0 slot0 = x_0
    f32x4 s0[4];
    #pragma unroll
    for (int tt = 0; tt < 4; ++tt)
      s0[tt] = __builtin_amdgcn_mfma_f32_16x16x32_f16(ax, wmx[tt], splat4(bia1[tt]), 0, 0, 0);
    if (l < 32)
      *(f32x4*)((char*)Gx + gpwr) = (f32x4){s0[0][0], s0[1][0], s0[2][0], s0[3][0]};
  }
  barrier_lds();

  float4 xv = make_float4(0.f, 0.f, 0.f, 0.f);
  float c = 0.0f;

  // phase body. RD/WR: hstate byte offsets; GRD/GWR: G-parity byte offsets.
  auto phase = [&](int p, int RD, int WR, int GRD, int GWR) {
    // bulk x loads (consumed at p%16==8; float across lgkm-only barriers)
    if (isx && (p & 15) == 0 && (p + 16 + xtr) < T_STEPS)
      xv = *(const float4*)(xsrc + (size_t)(p + 16 + xtr) * 32);

    if (role == 0) {
      // ---- post-L1: finalize L1 step p ----
      if (p < T_STEPS) {
        const char* hb = hsbase + RD;
        const half8 a1 = *(const half8*)(hb);         // ks0: h1 lo
        const half8 a2 = *(const half8*)(hb + 128);   // ks1: h1 hi
        const f32x4 vv = *(const f32x4*)((const char*)Gx + GRD + gprd);
        f32x4 acc[4];
        #pragma unroll
        for (int tt = 0; tt < 4; ++tt) {
          acc[tt] = __builtin_amdgcn_mfma_f32_16x16x32_f16(a1, wbh[tt][0], splat4(vv[tt]), 0, 0, 0);
          acc[tt] = __builtin_amdgcn_mfma_f32_16x16x32_f16(a2, wbh[tt][1], acc[tt], 0, 0, 0);
        }
        if (l < 32) {
          const float gi = sigm2 (acc[0][0]);
          const float gf = sigm2 (acc[1][0]);
          const float gg = tanhg2(acc[2][0]);
          const float go = sigm2 (acc[3][0]);
          c = gf * c + gi * gg;
          const float hv = go * tanhc(c);
          *(_Float16*)((char*)hstate + WR + hwofs) = (_Float16)hv;   // h1_p
        }
      }
    } else if (role == 1) {
      // ---- post-L2: finalize L2 step p-2 ----
      if (p >= 2) {
        const char* hb = hsbase + RD;
        const half8 a3 = *(const half8*)(hb + 256);   // ks2: h2 lo
        const half8 a4 = *(const half8*)(hb + 384);   // ks3: h2 hi
        const f32x4 vv = *(const f32x4*)((const char*)Gh1 + GRD + gprd);
        f32x4 acc[4];
        #pragma unroll
        for (int tt = 0; tt < 4; ++tt) {
          acc[tt] = __builtin_amdgcn_mfma_f32_16x16x32_f16(a3, wbh[tt][0], splat4(vv[tt]), 0, 0, 0);
          acc[tt] = __builtin_amdgcn_mfma_f32_16x16x32_f16(a4, wbh[tt][1], acc[tt], 0, 0, 0);
        }
        if (l < 32) {
          const float gi = sigm2 (acc[0][0]);
          const float gf = sigm2 (acc[1][0]);
          const float gg = tanhg2(acc[2][0]);
          const float go = sigm2 (acc[3][0]);
          c = gf * c + gi * gg;
          const float hv = go * tanhc(c);
          *(_Float16*)((char*)hstate + WR + hwofs) = (_Float16)hv;   // h2_{p-2}
          if (p == T_STEPS + 1) hfin[abm][u] = hv;                   // h2_{T-1}
        }
      }
    } else {
      // ---- mid: partials (no acts) ----
      // (a) Gh1 partial for L2 step p-1 (reads h1_{p-1}, stable post-barrier)
      if (p >= 1 && p <= T_STEPS) {
        const char* hb = hsbase + RD;
        const half8 b1lo = *(const half8*)(hb);         // ks0
        const half8 b1hi = *(const half8*)(hb + 128);   // ks1
        f32x4 tq[4];
        #pragma unroll
        for (int tt = 0; tt < 4; ++tt) {
          tq[tt] = __builtin_amdgcn_mfma_f32_16x16x32_f16(b1lo, wbh[tt][0], splat4(bia2[tt]), 0, 0, 0);
          tq[tt] = __builtin_amdgcn_mfma_f32_16x16x32_f16(b1hi, wbh[tt][1], tq[tt], 0, 0, 0);
        }
        if (l < 32)
          *(f32x4*)((char*)Gh1 + GWR + gpwr) = (f32x4){tq[0][0], tq[1][0], tq[2][0], tq[3][0]};
      }
      // (b) Gx partial for L1 step p+1 (x window stable)
      if (p + 1 < T_STEPS) {
        const int pn = p + 1;
        const half8 ax = *(const half8*)(xwbase + ((pn >> 4) & 1) * 2048 + (pn & 15) * 128);
        f32x4 sx[4];
        #pragma unroll
        for (int tt = 0; tt < 4; ++tt)
          sx[tt] = __builtin_amdgcn_mfma_f32_16x16x32_f16(ax, wmx[tt], splat4(bia1[tt]), 0, 0, 0);
        if (l < 32)
          *(f32x4*)((char*)Gx + GWR + gpwr) = (f32x4){sx[0][0], sx[1][0], sx[2][0], sx[3][0]};
      }
    }

    // stage the register-held x window (loaded 8 phases ago)
    if (isx && (p & 15) == 8 && (p + 8 + xtr) < T_STEPS)
      *(half4*)((char*)xbig + (((p >> 4) + 1) & 1) * 2048 + xtr * 128 + xbm * 64 + xii * 8) = cvt4(xv);
  };

  // phases 0..T_STEPS+1; even: h read buf1/write buf0, G read par0/write par1
  for (int p2 = 0; p2 <= T_STEPS; p2 += 2) {
    phase(p2,     512, 0,   0,    2048);
    barrier_lds();
    phase(p2 + 1, 0,   512, 2048, 0);
    barrier_lds();
  }

  __syncthreads();   // full drain before epilogue

  // ---- head: y = LN(relu(hT@fc1^T+b1)@fc2^T+b2), 2 batch rows ----
  if (t < 256) {
    const int bi = t >> 7, j = t & 127;
    float a = fc1_b[j];
    const float4* w4 = (const float4*)(fc1_w + j * 64);
    const float4* h4 = (const float4*)hfin[bi];
    #pragma unroll
    for (int qq = 0; qq < 16; ++qq) {
      float4 wv = w4[qq]; float4 hv = h4[qq];
      a += wv.x * hv.x + wv.y * hv.y + wv.z * hv.z + wv.w * hv.w;
    }
    y1s[bi][j] = fmaxf(a, 0.0f);
  }
  __syncthreads();
  if (t < 256) {
    const int bi = t >> 7, j = t & 127;
    float a = fc2_b[j];
    const float4* w4 = (const float4*)(fc2_w + j * 128);
    const float4* y4 = (const float4*)y1s[bi];
    #pragma unroll
    for (int qq = 0; qq < 32; ++qq) {
      float4 wv = w4[qq]; float4 yv = y4[qq];
      a += wv.x * yv.x + wv.y * yv.y + wv.z * yv.z + wv.w * yv.w;
    }
    y2s[bi][j] = a;
  }
  __syncthreads();
  if (t < 128) {
    const int bi = t >> 6, jj = t & 63;
    float s  = y2s[bi][jj] + y2s[bi][64 + jj];
    float qs = y2s[bi][jj] * y2s[bi][jj] + y2s[bi][64 + jj] * y2s[bi][64 + jj];
    #pragma unroll
    for (int off = 32; off > 0; off >>= 1) {
      s  += __shfl_down(s, off, 64);
      qs += __shfl_down(qs, off, 64);
    }
    if (jj == 0) {
      const float mu  = s * (1.0f / 128.0f);
      const float var = qs * (1.0f / 128.0f) - mu * mu;
      redmu[bi] = mu;
      redrs[bi] = rsqrtf(var + 1e-5f);
    }
  }
  __syncthreads();
  if (t < 256) {
    const int bi = t >> 7, j = t & 127;
    out[(size_t)(2 * b + bi) * 128 + j] =
        (y2s[bi][j] - redmu[bi]) * redrs[bi] * ln_g[j] + ln_b[j];
  }
}

extern "C" void kernel_launch(void* const* d_in, const int* in_sizes, int n_in,
                              void* d_out, int out_size, void* d_ws, size_t ws_size,
                              hipStream_t stream) {
  const float* x     = (const float*)d_in[0];
  const float* w_ih1 = (const float*)d_in[1];
  const float* w_hh1 = (const float*)d_in[2];
  const float* b_ih1 = (const float*)d_in[3];
  const float* b_hh1 = (const float*)d_in[4];
  const float* w_ih2 = (const float*)d_in[5];
  const float* w_hh2 = (const float*)d_in[6];
  const float* b_ih2 = (const float*)d_in[7];
  const float* b_hh2 = (const float*)d_in[8];
  const float* fc1_w = (const float*)d_in[9];
  const float* fc1_b = (const float*)d_in[10];
  const float* fc2_w = (const float*)d_in[11];
  const float* fc2_b = (const float*)d_in[12];
  const float* ln_g  = (const float*)d_in[13];
  const float* ln_b  = (const float*)d_in[14];
  float* out = (float*)d_out;

  lstm_fused<<<NBLK, 768, 0, stream>>>(x, w_ih1, w_hh1, b_ih1, b_hh1,
                                       w_ih2, w_hh2, b_ih2, b_hh2,
                                       fc1_w, fc1_b, fc2_w, fc2_b,
                                       ln_g, ln_b, out);
}

// Round 14
// 520.511 us; speedup vs baseline: 1.2045x; 1.2045x over previous
//
#include <hip/hip_runtime.h>
#include <cstdint>
#include <cstddef>

#define T_STEPS 1024
#define NBLK    256   // 512 batch / 2 per block; 1 block per CU
#define LOG2E   1.4426950408889634f

typedef __attribute__((ext_vector_type(8))) _Float16 half8;
typedef __attribute__((ext_vector_type(4))) _Float16 half4;
typedef __attribute__((ext_vector_type(4))) float    f32x4;

static __device__ __forceinline__ float fexp2(float x) {
#if defined(__has_builtin) && __has_builtin(__builtin_amdgcn_exp2f)
  return __builtin_amdgcn_exp2f(x);
#else
  return __exp2f(x);
#endif
}
// pre-acts arrive PRE-SCALED by log2e (weights/bias scaled at load)
static __device__ __forceinline__ float sigm2(float a) {          // sigmoid(a/log2e)
  return __builtin_amdgcn_rcpf(1.0f + fexp2(-a));
}
static __device__ __forceinline__ float tanhg2(float a) {         // tanh(a/log2e)
  return 2.0f * __builtin_amdgcn_rcpf(1.0f + fexp2(-(a + a))) - 1.0f;
}
static __device__ __forceinline__ float tanhc(float c) {          // tanh(c), c unscaled
  return 1.0f - 2.0f * __builtin_amdgcn_rcpf(1.0f + fexp2(c * (2.0f * LOG2E)));
}

static __device__ __forceinline__ half8 load8s(const float* s, float sc) {
  float4 a = ((const float4*)s)[0];
  float4 b = ((const float4*)s)[1];
  half8 h;
  h[0] = (_Float16)(a.x * sc); h[1] = (_Float16)(a.y * sc);
  h[2] = (_Float16)(a.z * sc); h[3] = (_Float16)(a.w * sc);
  h[4] = (_Float16)(b.x * sc); h[5] = (_Float16)(b.y * sc);
  h[6] = (_Float16)(b.z * sc); h[7] = (_Float16)(b.w * sc);
  return h;
}
static __device__ __forceinline__ half4 cvt4(float4 v) {
  half4 h; h[0] = (_Float16)v.x; h[1] = (_Float16)v.y; h[2] = (_Float16)v.z; h[3] = (_Float16)v.w;
  return h;
}

// lgkm-only workgroup barrier: drains LDS ops (producer->consumer visibility)
// but leaves global loads in flight across the barrier.
static __device__ __forceinline__ void barrier_lds() {
  __asm__ volatile("s_waitcnt lgkmcnt(0)\n\ts_barrier" ::: "memory");
}

// R14 = R11 (verified best: 542 us, best-dispatch 522) with ONE change:
// all x-prefetch/staging machinery moved to the L1 waves (waves 0-3, lanes
// 32-63, 2 float4 per lane per 16-step window). L2 waves now carry ZERO x
// code (wave-uniform branch skip) -> they issue their post-barrier h2 reads
// sooner and arrive at the barrier sooner, shrinking barrier-arrival spread.
// L1 waves have the issue slack (12 vs 16 MFMA per phase).
// (R12/R13's 12-wave K-split REVERTED: correct but slower — the mid wave's
// read->8 MFMA->partial-write chain became the barrier's longest pole and LDS
// traffic grew; 627 us vs 542.)
//
// Structure (R11): grid 256 x 512 threads, batch {2b,2b+1} at MFMA A-rows 0,4
// (D reg0: batch0 lanes 0-15, batch1 lanes 16-31). Waves 0-3: L1 (step p),
// 4-7: L2 (step p-2, h1-ksteps pre-issued one phase early into accq, h2-ksteps
// post-barrier -> acts start after 8 MFMAs). Wave owns all 4 gate types of 16
// units -> in-wave acts. ONE lgkm-only barrier per phase; loop unrolled x2
// (compile-time buffer offsets). hstate[buf][kstep][batch][32] bank-disjoint
// (R9-verified); bias folded into MFMA C-init; log2e pre-scale -> native
// v_exp_f32 acts.
// MFMA layouts (m89/m120-verified): A[m=l&15][k=(l>>4)*8+j];
// B[k=(l>>4)*8+j][n=l&15]; D[row=(l>>4)*4+reg][col=l&15].
__global__ __launch_bounds__(512, 2) void lstm_fused(
    const float* __restrict__ x,
    const float* __restrict__ w_ih1, const float* __restrict__ w_hh1,
    const float* __restrict__ b_ih1, const float* __restrict__ b_hh1,
    const float* __restrict__ w_ih2, const float* __restrict__ w_hh2,
    const float* __restrict__ b_ih2, const float* __restrict__ b_hh2,
    const float* __restrict__ fc1_w, const float* __restrict__ fc1_b,
    const float* __restrict__ fc2_w, const float* __restrict__ fc2_b,
    const float* __restrict__ ln_g, const float* __restrict__ ln_b,
    float* __restrict__ out)
{
  // ks0 = h1[0:32), ks1 = h1[32:64), ks2 = h2[0:32), ks3 = h2[32:64)
  __shared__ __align__(16) _Float16 hstate[2][4][2][32];   // 1 KB, bank-disjoint
  __shared__ __align__(16) _Float16 xbig[2][16][2][32];    // 4 KB
  __shared__ __align__(16) float hfin[2][64];
  __shared__ __align__(16) float y1s[2][128];
  __shared__ __align__(16) float y2s[2][128];
  __shared__ float redmu[2], redrs[2];

  const int t   = threadIdx.x;
  const int b   = blockIdx.x;
  const int l   = t & 63;
  const int w   = t >> 6;       // wave 0..7
  const int ly  = w >> 2;       // 0=L1, 1=L2
  const int wq  = w & 3;        // unit group
  const int col = l & 15;
  const int q   = l >> 4;       // quad
  const int bm  = ((l & 15) >> 2) & 1;  // batch whose A-row this lane serves

  // ---- init: zero h-state (both buffers: 512 halves, one per thread) ----
  ((_Float16*)hstate)[t] = (_Float16)0.0f;

  // ---- init: preload x[0..16) into xbig buf0 ----
  if (t < 256) {
    const int b0 = t >> 7, r0 = t & 127, tr0 = r0 >> 3, ii0 = r0 & 7;
    const float4 v = *(const float4*)(x + ((size_t)(2 * b + b0) * T_STEPS + tr0) * 32 + ii0 * 4);
    *(half4*)((char*)xbig + tr0 * 128 + b0 * 64 + ii0 * 8) = cvt4(v);
  }

  // ---- stationary weights (pre-scaled by log2e) -> B frags wb[tile][kstep] ----
  half8 wb[4][4];
  {
    const int ko = q * 8;
    #pragma unroll
    for (int tt = 0; tt < 4; ++tt) {
      const int r = tt * 64 + wq * 16 + col;
      if (ly == 0) {
        wb[tt][0] = load8s(w_ih1 + r * 32 + ko, LOG2E);        // x kstep
        wb[tt][1] = load8s(w_hh1 + r * 64 + ko, LOG2E);        // h1 lo
        wb[tt][2] = load8s(w_hh1 + r * 64 + 32 + ko, LOG2E);   // h1 hi
        wb[tt][3] = wb[tt][0];                                 // unused
      } else {
        wb[tt][0] = load8s(w_ih2 + r * 64 + ko, LOG2E);        // h1 lo
        wb[tt][1] = load8s(w_ih2 + r * 64 + 32 + ko, LOG2E);   // h1 hi
        wb[tt][2] = load8s(w_hh2 + r * 64 + ko, LOG2E);        // h2 lo
        wb[tt][3] = load8s(w_hh2 + r * 64 + 32 + ko, LOG2E);   // h2 hi
      }
    }
  }

  // ---- per-tile bias (scaled by log2e), used as MFMA C-init ----
  float bia[4];
  {
    const float* bi_ = ly ? b_ih2 : b_ih1;
    const float* bh_ = ly ? b_hh2 : b_hh1;
    #pragma unroll
    for (int tt = 0; tt < 4; ++tt) {
      const int r = tt * 64 + wq * 16 + col;
      bia[tt] = (bi_[r] + bh_[r]) * LOG2E;
    }
  }
  // act-lane mapping (lanes 0-31): unit u, batch = l>>4
  const int u   = wq * 16 + col;
  const int abm = l >> 4;
  const int hwofs = ((ly ? 2 : 0) + (u >> 5)) * 128 + abm * 64 + (u & 31) * 2;

  // ---- x-prefetch lanes: waves 0-3 ONLY, lanes 32-63 (128 lanes, 2 f4 each) ----
  const bool isx = (w < 4) && (l >= 32);
  const int g   = w * 32 + (l - 32);      // 0..127
  const int xtr = g >> 3;                 // step-in-window 0..15
  const int xii = g & 7;                  // float4 index 0..7
  const float* xsrc0 = x + ((size_t)(2 * b + 0) * T_STEPS) * 32 + xii * 4;
  const float* xsrc1 = x + ((size_t)(2 * b + 1) * T_STEPS) * 32 + xii * 4;

  const char* hsbase = (const char*)hstate + bm * 64 + q * 16;  // + buf*512 + ks*128
  const char* xwbase = (const char*)xbig   + bm * 64 + q * 16;  // + buf*2048 + slot*128

  __syncthreads();

  // ---- pre-issue phase-0 x-kstep MFMAs (L1 step 0), C = bias ----
  f32x4 accp[4];   // L1 carried: x-ksteps of step p+1
  f32x4 accq[4];   // L2 carried: h1-ksteps of step p-1
  #pragma unroll
  for (int tt = 0; tt < 4; ++tt) {
    accp[tt] = (f32x4){bia[tt], bia[tt], bia[tt], bia[tt]};
    accq[tt] = accp[tt];
  }
  if (ly == 0) {
    const half8 ax = *(const half8*)xwbase;   // buf0 slot0 = x_0
    #pragma unroll
    for (int tt = 0; tt < 4; ++tt)
      accp[tt] = __builtin_amdgcn_mfma_f32_16x16x32_f16(ax, wb[tt][0], accp[tt], 0, 0, 0);
  }

  float4 xv0 = make_float4(0.f, 0.f, 0.f, 0.f);
  float4 xv1 = make_float4(0.f, 0.f, 0.f, 0.f);
  float c = 0.0f;

  // phase body: writes -> buf WR, reads -> buf RD (RD = 512 - WR)
  auto phase = [&](int p, int RD, int WR) {
    // bulk x loads (L1 waves only; consumed at p%16==8; float across barriers)
    if (isx && (p & 15) == 0 && (p + 16 + xtr) < T_STEPS) {
      xv0 = *(const float4*)(xsrc0 + (size_t)(p + 16 + xtr) * 32);
      xv1 = *(const float4*)(xsrc1 + (size_t)(p + 16 + xtr) * 32);
    }

    if (ly == 0) {
      // ---- L1, step t=p ----
      if (p < T_STEPS) {
        const char* hb = hsbase + RD;
        const half8 a1 = *(const half8*)(hb);         // ks0: h1 lo
        const half8 a2 = *(const half8*)(hb + 128);   // ks1: h1 hi
        f32x4 acc[4];
        #pragma unroll
        for (int tt = 0; tt < 4; ++tt) {
          acc[tt] = __builtin_amdgcn_mfma_f32_16x16x32_f16(a1, wb[tt][1], accp[tt], 0, 0, 0);
          acc[tt] = __builtin_amdgcn_mfma_f32_16x16x32_f16(a2, wb[tt][2], acc[tt], 0, 0, 0);
        }
        // pre-issue x-ksteps for step p+1 BEFORE acts (fills pipe under act VALU)
        if (p + 1 < T_STEPS) {
          const int pn = p + 1;
          const half8 ax = *(const half8*)(xwbase + ((pn >> 4) & 1) * 2048 + (pn & 15) * 128);
          #pragma unroll
          for (int tt = 0; tt < 4; ++tt)
            accp[tt] = __builtin_amdgcn_mfma_f32_16x16x32_f16(ax, wb[tt][0],
                         (f32x4){bia[tt], bia[tt], bia[tt], bia[tt]}, 0, 0, 0);
        }
        if (l < 32) {
          const float gi = sigm2 (acc[0][0]);
          const float gf = sigm2 (acc[1][0]);
          const float gg = tanhg2(acc[2][0]);
          const float go = sigm2 (acc[3][0]);
          c = gf * c + gi * gg;
          const float hv = go * tanhc(c);
          *(_Float16*)((char*)hstate + WR + hwofs) = (_Float16)hv;   // h1_p
        }
      }
      // stage the register-held x window (loaded 8 phases ago)
      if (isx && (p & 15) == 8 && (p + 8 + xtr) < T_STEPS) {
        const int bb2 = (((p >> 4) + 1) & 1) * 2048 + xtr * 128 + xii * 8;
        *(half4*)((char*)xbig + bb2)      = cvt4(xv0);
        *(half4*)((char*)xbig + bb2 + 64) = cvt4(xv1);
      }
    } else {
      // ---- L2, finalize step t=p-2 (h1 ksteps already in accq) ----
      if (p >= 2) {
        const char* hb = hsbase + RD;
        const half8 a2lo = *(const half8*)(hb + 256);   // ks2: h2 lo
        const half8 a2hi = *(const half8*)(hb + 384);   // ks3: h2 hi
        f32x4 acc[4];
        #pragma unroll
        for (int tt = 0; tt < 4; ++tt) {
          acc[tt] = __builtin_amdgcn_mfma_f32_16x16x32_f16(a2lo, wb[tt][2], accq[tt], 0, 0, 0);
          acc[tt] = __builtin_amdgcn_mfma_f32_16x16x32_f16(a2hi, wb[tt][3], acc[tt], 0, 0, 0);
        }
        // mid-phase: read h1_{p-1} + issue h1-ksteps for step p-1 (before acts)
        if (p <= T_STEPS) {
          const half8 b1lo = *(const half8*)(hsbase + RD);         // ks0
          const half8 b1hi = *(const half8*)(hsbase + RD + 128);   // ks1
          #pragma unroll
          for (int tt = 0; tt < 4; ++tt) {
            accq[tt] = __builtin_amdgcn_mfma_f32_16x16x32_f16(b1lo, wb[tt][0],
                         (f32x4){bia[tt], bia[tt], bia[tt], bia[tt]}, 0, 0, 0);
            accq[tt] = __builtin_amdgcn_mfma_f32_16x16x32_f16(b1hi, wb[tt][1], accq[tt], 0, 0, 0);
          }
        }
        if (l < 32) {
          const float gi = sigm2 (acc[0][0]);
          const float gf = sigm2 (acc[1][0]);
          const float gg = tanhg2(acc[2][0]);
          const float go = sigm2 (acc[3][0]);
          c = gf * c + gi * gg;
          const float hv = go * tanhc(c);
          *(_Float16*)((char*)hstate + WR + hwofs) = (_Float16)hv;   // h2_{p-2}
          if (p == T_STEPS + 1) hfin[abm][u] = hv;                   // h2_{T-1}
        }
      } else if (p == 1) {
        // first accq issue: h1-ksteps for step 0 (h1_0 in buf RD)
        const half8 b1lo = *(const half8*)(hsbase + RD);
        const half8 b1hi = *(const half8*)(hsbase + RD + 128);
        #pragma unroll
        for (int tt = 0; tt < 4; ++tt) {
          accq[tt] = __builtin_amdgcn_mfma_f32_16x16x32_f16(b1lo, wb[tt][0],
                       (f32x4){bia[tt], bia[tt], bia[tt], bia[tt]}, 0, 0, 0);
          accq[tt] = __builtin_amdgcn_mfma_f32_16x16x32_f16(b1hi, wb[tt][1], accq[tt], 0, 0, 0);
        }
      }
    }
  };

  // phases 0..T_STEPS+1 (L2 skew 2); even: read buf1/write buf0, odd: reverse
  for (int p2 = 0; p2 <= T_STEPS; p2 += 2) {
    phase(p2, 512, 0);
    barrier_lds();
    phase(p2 + 1, 0, 512);
    barrier_lds();
  }

  __syncthreads();   // full drain before epilogue

  // ---- head: y = LN(relu(hT@fc1^T+b1)@fc2^T+b2), 2 batch rows ----
  if (t < 256) {
    const int bi = t >> 7, j = t & 127;
    float a = fc1_b[j];
    const float4* w4 = (const float4*)(fc1_w + j * 64);
    const float4* h4 = (const float4*)hfin[bi];
    #pragma unroll
    for (int qq = 0; qq < 16; ++qq) {
      float4 wv = w4[qq]; float4 hv = h4[qq];
      a += wv.x * hv.x + wv.y * hv.y + wv.z * hv.z + wv.w * hv.w;
    }
    y1s[bi][j] = fmaxf(a, 0.0f);
  }
  __syncthreads();
  if (t < 256) {
    const int bi = t >> 7, j = t & 127;
    float a = fc2_b[j];
    const float4* w4 = (const float4*)(fc2_w + j * 128);
    const float4* y4 = (const float4*)y1s[bi];
    #pragma unroll
    for (int qq = 0; qq < 32; ++qq) {
      float4 wv = w4[qq]; float4 yv = y4[qq];
      a += wv.x * yv.x + wv.y * yv.y + wv.z * yv.z + wv.w * yv.w;
    }
    y2s[bi][j] = a;
  }
  __syncthreads();
  if (t < 128) {
    const int bi = t >> 6, jj = t & 63;
    float s  = y2s[bi][jj] + y2s[bi][64 + jj];
    float qs = y2s[bi][jj] * y2s[bi][jj] + y2s[bi][64 + jj] * y2s[bi][64 + jj];
    #pragma unroll
    for (int off = 32; off > 0; off >>= 1) {
      s  += __shfl_down(s, off, 64);
      qs += __shfl_down(qs, off, 64);
    }
    if (jj == 0) {
      const float mu  = s * (1.0f / 128.0f);
      const float var = qs * (1.0f / 128.0f) - mu * mu;
      redmu[bi] = mu;
      redrs[bi] = rsqrtf(var + 1e-5f);
    }
  }
  __syncthreads();
  if (t < 256) {
    const int bi = t >> 7, j = t & 127;
    out[(size_t)(2 * b + bi) * 128 + j] =
        (y2s[bi][j] - redmu[bi]) * redrs[bi] * ln_g[j] + ln_b[j];
  }
}

extern "C" void kernel_launch(void* const* d_in, const int* in_sizes, int n_in,
                              void* d_out, int out_size, void* d_ws, size_t ws_size,
                              hipStream_t stream) {
  const float* x     = (const float*)d_in[0];
  const float* w_ih1 = (const float*)d_in[1];
  const float* w_hh1 = (const float*)d_in[2];
  const float* b_ih1 = (const float*)d_in[3];
  const float* b_hh1 = (const float*)d_in[4];
  const float* w_ih2 = (const float*)d_in[5];
  const float* w_hh2 = (const float*)d_in[6];
  const float* b_ih2 = (const float*)d_in[7];
  const float* b_hh2 = (const float*)d_in[8];
  const float* fc1_w = (const float*)d_in[9];
  const float* fc1_b = (const float*)d_in[10];
  const float* fc2_w = (const float*)d_in[11];
  const float* fc2_b = (const float*)d_in[12];
  const float* ln_g  = (const float*)d_in[13];
  const float* ln_b  = (const float*)d_in[14];
  float* out = (float*)d_out;

  lstm_fused<<<NBLK, 512, 0, stream>>>(x, w_ih1, w_hh1, b_ih1, b_hh1,
                                       w_ih2, w_hh2, b_ih2, b_hh2,
                                       fc1_w, fc1_b, fc2_w, fc2_b,
                                       ln_g, ln_b, out);
}

// Round 15
// 510.161 us; speedup vs baseline: 1.2290x; 1.0203x over previous
//
#include <hip/hip_runtime.h>
#include <cstdint>
#include <cstddef>

#define T_STEPS 1024
#define NBLK    256   // 512 batch / 2 per block; 1 block per CU
#define LOG2E   1.4426950408889634f

typedef __attribute__((ext_vector_type(8))) _Float16 half8;
typedef __attribute__((ext_vector_type(4))) _Float16 half4;
typedef __attribute__((ext_vector_type(4))) float    f32x4;

static __device__ __forceinline__ float fexp2(float x) {
#if defined(__has_builtin) && __has_builtin(__builtin_amdgcn_exp2f)
  return __builtin_amdgcn_exp2f(x);
#else
  return __exp2f(x);
#endif
}
// pre-acts arrive PRE-SCALED by log2e (weights/bias scaled at load)
static __device__ __forceinline__ float sigm2(float a) {          // sigmoid(a/log2e)
  return __builtin_amdgcn_rcpf(1.0f + fexp2(-a));
}
static __device__ __forceinline__ float tanhg2(float a) {         // tanh(a/log2e)
  return 2.0f * __builtin_amdgcn_rcpf(1.0f + fexp2(-(a + a))) - 1.0f;
}
static __device__ __forceinline__ float tanhc(float c) {          // tanh(c), c unscaled
  return 1.0f - 2.0f * __builtin_amdgcn_rcpf(1.0f + fexp2(c * (2.0f * LOG2E)));
}

static __device__ __forceinline__ half8 load8s(const float* s, float sc) {
  float4 a = ((const float4*)s)[0];
  float4 b = ((const float4*)s)[1];
  half8 h;
  h[0] = (_Float16)(a.x * sc); h[1] = (_Float16)(a.y * sc);
  h[2] = (_Float16)(a.z * sc); h[3] = (_Float16)(a.w * sc);
  h[4] = (_Float16)(b.x * sc); h[5] = (_Float16)(b.y * sc);
  h[6] = (_Float16)(b.z * sc); h[7] = (_Float16)(b.w * sc);
  return h;
}
static __device__ __forceinline__ half4 cvt4(float4 v) {
  half4 h; h[0] = (_Float16)v.x; h[1] = (_Float16)v.y; h[2] = (_Float16)v.z; h[3] = (_Float16)v.w;
  return h;
}
static __device__ __forceinline__ f32x4 splat4(float v) { return (f32x4){v, v, v, v}; }

// lgkm-only workgroup barrier: drains LDS ops (producer->consumer visibility)
// but leaves global loads in flight across the barrier.
static __device__ __forceinline__ void barrier_lds() {
  __asm__ volatile("s_waitcnt lgkmcnt(0)\n\ts_barrier" ::: "memory");
}

// R15 = R14 (verified best: 520 us / best-dispatch 491) + zero-wait phase top:
// every A-fragment stable >=1 phase is ds_read ONE PHASE BEFORE its MFMAs, so
// those MFMAs issue immediately post-barrier from registers, filling the
// ~130-cyc dead window where both waves of a SIMD previously stalled on
// post-barrier ds_read simultaneously.
//  L1 phase p: top = 4 accp MFMAs (x-frag of step p, read at p-1; C=bias) +
//    ds_read h1_{p-1} + ds_read x-frag for step p+1; then 8 h-MFMAs chain
//    accp when h1 lands; acts; write h1_p.
//  L2 phase p: top = 8 accq MFMAs (h1_{p-2} frags, read at p-1; C=bias) +
//    ds_read h2_{p-3} (finalize input) + ds_read h1_{p-1} (for next accq);
//    then 8 finalize MFMAs chain accq when h2 lands; acts; write h2_{p-2}.
//    (skew 2 as R11; accq/accp now phase-local — created & consumed in-phase.)
// Everything else as R14: grid 256 x 512, batch {2b,2b+1} at A-rows 0,4;
// waves 0-3 L1 / 4-7 L2; in-wave acts; ONE lgkm-only barrier/phase; x-prefetch
// on L1 waves only; hstate[buf][kstep][batch][32] bank-disjoint; bias in MFMA
// C-init; log2e pre-scale -> native v_exp_f32 acts; loop unrolled x2.
// MFMA layouts (m89/m120-verified): A[m=l&15][k=(l>>4)*8+j];
// B[k=(l>>4)*8+j][n=l&15]; D[row=(l>>4)*4+reg][col=l&15].
__global__ __launch_bounds__(512, 2) void lstm_fused(
    const float* __restrict__ x,
    const float* __restrict__ w_ih1, const float* __restrict__ w_hh1,
    const float* __restrict__ b_ih1, const float* __restrict__ b_hh1,
    const float* __restrict__ w_ih2, const float* __restrict__ w_hh2,
    const float* __restrict__ b_ih2, const float* __restrict__ b_hh2,
    const float* __restrict__ fc1_w, const float* __restrict__ fc1_b,
    const float* __restrict__ fc2_w, const float* __restrict__ fc2_b,
    const float* __restrict__ ln_g, const float* __restrict__ ln_b,
    float* __restrict__ out)
{
  // ks0 = h1[0:32), ks1 = h1[32:64), ks2 = h2[0:32), ks3 = h2[32:64)
  __shared__ __align__(16) _Float16 hstate[2][4][2][32];   // 1 KB, bank-disjoint
  __shared__ __align__(16) _Float16 xbig[2][16][2][32];    // 4 KB
  __shared__ __align__(16) float hfin[2][64];
  __shared__ __align__(16) float y1s[2][128];
  __shared__ __align__(16) float y2s[2][128];
  __shared__ float redmu[2], redrs[2];

  const int t   = threadIdx.x;
  const int b   = blockIdx.x;
  const int l   = t & 63;
  const int w   = t >> 6;       // wave 0..7
  const int ly  = w >> 2;       // 0=L1, 1=L2
  const int wq  = w & 3;        // unit group
  const int col = l & 15;
  const int q   = l >> 4;       // quad
  const int bm  = ((l & 15) >> 2) & 1;  // batch whose A-row this lane serves

  // ---- init: zero h-state (both buffers: 512 halves, one per thread) ----
  ((_Float16*)hstate)[t] = (_Float16)0.0f;

  // ---- init: preload x[0..16) into xbig buf0 ----
  if (t < 256) {
    const int b0 = t >> 7, r0 = t & 127, tr0 = r0 >> 3, ii0 = r0 & 7;
    const float4 v = *(const float4*)(x + ((size_t)(2 * b + b0) * T_STEPS + tr0) * 32 + ii0 * 4);
    *(half4*)((char*)xbig + tr0 * 128 + b0 * 64 + ii0 * 8) = cvt4(v);
  }

  // ---- stationary weights (pre-scaled by log2e) -> B frags wb[tile][kstep] ----
  half8 wb[4][4];
  {
    const int ko = q * 8;
    #pragma unroll
    for (int tt = 0; tt < 4; ++tt) {
      const int r = tt * 64 + wq * 16 + col;
      if (ly == 0) {
        wb[tt][0] = load8s(w_ih1 + r * 32 + ko, LOG2E);        // x kstep
        wb[tt][1] = load8s(w_hh1 + r * 64 + ko, LOG2E);        // h1 lo
        wb[tt][2] = load8s(w_hh1 + r * 64 + 32 + ko, LOG2E);   // h1 hi
        wb[tt][3] = wb[tt][0];                                 // unused
      } else {
        wb[tt][0] = load8s(w_ih2 + r * 64 + ko, LOG2E);        // h1 lo
        wb[tt][1] = load8s(w_ih2 + r * 64 + 32 + ko, LOG2E);   // h1 hi
        wb[tt][2] = load8s(w_hh2 + r * 64 + ko, LOG2E);        // h2 lo
        wb[tt][3] = load8s(w_hh2 + r * 64 + 32 + ko, LOG2E);   // h2 hi
      }
    }
  }

  // ---- per-tile bias (scaled by log2e), used as MFMA C-init ----
  float bia[4];
  {
    const float* bi_ = ly ? b_ih2 : b_ih1;
    const float* bh_ = ly ? b_hh2 : b_hh1;
    #pragma unroll
    for (int tt = 0; tt < 4; ++tt) {
      const int r = tt * 64 + wq * 16 + col;
      bia[tt] = (bi_[r] + bh_[r]) * LOG2E;
    }
  }
  // act-lane mapping (lanes 0-31): unit u, batch = l>>4
  const int u   = wq * 16 + col;
  const int abm = l >> 4;
  const int hwofs = ((ly ? 2 : 0) + (u >> 5)) * 128 + abm * 64 + (u & 31) * 2;

  // ---- x-prefetch lanes: waves 0-3 ONLY, lanes 32-63 (128 lanes, 2 f4 each) ----
  const bool isx = (w < 4) && (l >= 32);
  const int g   = w * 32 + (l - 32);      // 0..127
  const int xtr = g >> 3;                 // step-in-window 0..15
  const int xii = g & 7;                  // float4 index 0..7
  const float* xsrc0 = x + ((size_t)(2 * b + 0) * T_STEPS) * 32 + xii * 4;
  const float* xsrc1 = x + ((size_t)(2 * b + 1) * T_STEPS) * 32 + xii * 4;

  const char* hsbase = (const char*)hstate + bm * 64 + q * 16;  // + buf*512 + ks*128
  const char* xwbase = (const char*)xbig   + bm * 64 + q * 16;  // + buf*2048 + slot*128

  __syncthreads();

  // loop-carried pre-read fragments
  half8 xf;            // L1: x-frag of the step processed NEXT phase-top
  half8 h1f0, h1f1;    // L2: h1 frags consumed at NEXT phase-top
  if (ly == 0) xf = *(const half8*)xwbase;   // x_0 (buf0 slot0)

  float4 xv0 = make_float4(0.f, 0.f, 0.f, 0.f);
  float4 xv1 = make_float4(0.f, 0.f, 0.f, 0.f);
  float c = 0.0f;

  // phase body: writes -> buf WR, reads -> buf RD (RD = 512 - WR)
  auto phase = [&](int p, int RD, int WR) {
    // bulk x loads (L1 waves only; consumed at p%16==8; float across barriers)
    if (isx && (p & 15) == 0 && (p + 16 + xtr) < T_STEPS) {
      xv0 = *(const float4*)(xsrc0 + (size_t)(p + 16 + xtr) * 32);
      xv1 = *(const float4*)(xsrc1 + (size_t)(p + 16 + xtr) * 32);
    }

    if (ly == 0) {
      // ---- L1, step t=p ----
      if (p < T_STEPS) {
        // TOP: accp MFMAs from reg-held x-frag (no wait), C = bias
        f32x4 accp[4];
        #pragma unroll
        for (int tt = 0; tt < 4; ++tt)
          accp[tt] = __builtin_amdgcn_mfma_f32_16x16x32_f16(xf, wb[tt][0],
                       splat4(bia[tt]), 0, 0, 0);
        // issue ds_reads: h1_{p-1} frags + next x-frag
        const char* hb = hsbase + RD;
        const half8 a1 = *(const half8*)(hb);         // ks0: h1 lo
        const half8 a2 = *(const half8*)(hb + 128);   // ks1: h1 hi
        if (p + 1 < T_STEPS) {
          const int pn = p + 1;
          xf = *(const half8*)(xwbase + ((pn >> 4) & 1) * 2048 + (pn & 15) * 128);
        }
        // chain h-MFMAs when h1 lands
        f32x4 acc[4];
        #pragma unroll
        for (int tt = 0; tt < 4; ++tt) {
          acc[tt] = __builtin_amdgcn_mfma_f32_16x16x32_f16(a1, wb[tt][1], accp[tt], 0, 0, 0);
          acc[tt] = __builtin_amdgcn_mfma_f32_16x16x32_f16(a2, wb[tt][2], acc[tt], 0, 0, 0);
        }
        if (l < 32) {
          const float gi = sigm2 (acc[0][0]);
          const float gf = sigm2 (acc[1][0]);
          const float gg = tanhg2(acc[2][0]);
          const float go = sigm2 (acc[3][0]);
          c = gf * c + gi * gg;
          const float hv = go * tanhc(c);
          *(_Float16*)((char*)hstate + WR + hwofs) = (_Float16)hv;   // h1_p
        }
      }
      // stage the register-held x window (loaded 8 phases ago)
      if (isx && (p & 15) == 8 && (p + 8 + xtr) < T_STEPS) {
        const int bb2 = (((p >> 4) + 1) & 1) * 2048 + xtr * 128 + xii * 8;
        *(half4*)((char*)xbig + bb2)      = cvt4(xv0);
        *(half4*)((char*)xbig + bb2 + 64) = cvt4(xv1);
      }
    } else {
      // ---- L2, finalize step t=p-2 ----
      f32x4 accq[4];
      if (p >= 2 && p <= T_STEPS + 1) {
        // TOP: accq MFMAs from reg-held h1_{p-2} frags (read last phase), C = bias
        #pragma unroll
        for (int tt = 0; tt < 4; ++tt) {
          accq[tt] = __builtin_amdgcn_mfma_f32_16x16x32_f16(h1f0, wb[tt][0],
                       splat4(bia[tt]), 0, 0, 0);
          accq[tt] = __builtin_amdgcn_mfma_f32_16x16x32_f16(h1f1, wb[tt][1], accq[tt], 0, 0, 0);
        }
      }
      // issue ds_reads: h2 (finalize input) + h1_{p-1} (for next phase-top)
      half8 a2lo, a2hi;
      if (p >= 2 && p <= T_STEPS + 1) {
        const char* hb = hsbase + RD;
        a2lo = *(const half8*)(hb + 256);   // ks2: h2 lo
        a2hi = *(const half8*)(hb + 384);   // ks3: h2 hi
      }
      if (p >= 1 && p <= T_STEPS) {
        h1f0 = *(const half8*)(hsbase + RD);         // ks0: h1_{p-1} lo
        h1f1 = *(const half8*)(hsbase + RD + 128);   // ks1: h1_{p-1} hi
      }
      if (p >= 2 && p <= T_STEPS + 1) {
        // chain finalize MFMAs when h2 lands
        f32x4 acc[4];
        #pragma unroll
        for (int tt = 0; tt < 4; ++tt) {
          acc[tt] = __builtin_amdgcn_mfma_f32_16x16x32_f16(a2lo, wb[tt][2], accq[tt], 0, 0, 0);
          acc[tt] = __builtin_amdgcn_mfma_f32_16x16x32_f16(a2hi, wb[tt][3], acc[tt], 0, 0, 0);
        }
        if (l < 32) {
          const float gi = sigm2 (acc[0][0]);
          const float gf = sigm2 (acc[1][0]);
          const float gg = tanhg2(acc[2][0]);
          const float go = sigm2 (acc[3][0]);
          c = gf * c + gi * gg;
          const float hv = go * tanhc(c);
          *(_Float16*)((char*)hstate + WR + hwofs) = (_Float16)hv;   // h2_{p-2}
          if (p == T_STEPS + 1) hfin[abm][u] = hv;                   // h2_{T-1}
        }
      }
    }
  };

  // phases 0..T_STEPS+1 (L2 skew 2); even: read buf1/write buf0, odd: reverse
  for (int p2 = 0; p2 <= T_STEPS; p2 += 2) {
    phase(p2, 512, 0);
    barrier_lds();
    phase(p2 + 1, 0, 512);
    barrier_lds();
  }

  __syncthreads();   // full drain before epilogue

  // ---- head: y = LN(relu(hT@fc1^T+b1)@fc2^T+b2), 2 batch rows ----
  if (t < 256) {
    const int bi = t >> 7, j = t & 127;
    float a = fc1_b[j];
    const float4* w4 = (const float4*)(fc1_w + j * 64);
    const float4* h4 = (const float4*)hfin[bi];
    #pragma unroll
    for (int qq = 0; qq < 16; ++qq) {
      float4 wv = w4[qq]; float4 hv = h4[qq];
      a += wv.x * hv.x + wv.y * hv.y + wv.z * hv.z + wv.w * hv.w;
    }
    y1s[bi][j] = fmaxf(a, 0.0f);
  }
  __syncthreads();
  if (t < 256) {
    const int bi = t >> 7, j = t & 127;
    float a = fc2_b[j];
    const float4* w4 = (const float4*)(fc2_w + j * 128);
    const float4* y4 = (const float4*)y1s[bi];
    #pragma unroll
    for (int qq = 0; qq < 32; ++qq) {
      float4 wv = w4[qq]; float4 yv = y4[qq];
      a += wv.x * yv.x + wv.y * yv.y + wv.z * yv.z + wv.w * yv.w;
    }
    y2s[bi][j] = a;
  }
  __syncthreads();
  if (t < 128) {
    const int bi = t >> 6, jj = t & 63;
    float s  = y2s[bi][jj] + y2s[bi][64 + jj];
    float qs = y2s[bi][jj] * y2s[bi][jj] + y2s[bi][64 + jj] * y2s[bi][64 + jj];
    #pragma unroll
    for (int off = 32; off > 0; off >>= 1) {
      s  += __shfl_down(s, off, 64);
      qs += __shfl_down(qs, off, 64);
    }
    if (jj == 0) {
      const float mu  = s * (1.0f / 128.0f);
      const float var = qs * (1.0f / 128.0f) - mu * mu;
      redmu[bi] = mu;
      redrs[bi] = rsqrtf(var + 1e-5f);
    }
  }
  __syncthreads();
  if (t < 256) {
    const int bi = t >> 7, j = t & 127;
    out[(size_t)(2 * b + bi) * 128 + j] =
        (y2s[bi][j] - redmu[bi]) * redrs[bi] * ln_g[j] + ln_b[j];
  }
}

extern "C" void kernel_launch(void* const* d_in, const int* in_sizes, int n_in,
                              void* d_out, int out_size, void* d_ws, size_t ws_size,
                              hipStream_t stream) {
  const float* x     = (const float*)d_in[0];
  const float* w_ih1 = (const float*)d_in[1];
  const float* w_hh1 = (const float*)d_in[2];
  const float* b_ih1 = (const float*)d_in[3];
  const float* b_hh1 = (const float*)d_in[4];
  const float* w_ih2 = (const float*)d_in[5];
  const float* w_hh2 = (const float*)d_in[6];
  const float* b_ih2 = (const float*)d_in[7];
  const float* b_hh2 = (const float*)d_in[8];
  const float* fc1_w = (const float*)d_in[9];
  const float* fc1_b = (const float*)d_in[10];
  const float* fc2_w = (const float*)d_in[11];
  const float* fc2_b = (const float*)d_in[12];
  const float* ln_g  = (const float*)d_in[13];
  const float* ln_b  = (const float*)d_in[14];
  float* out = (float*)d_out;

  lstm_fused<<<NBLK, 512, 0, stream>>>(x, w_ih1, w_hh1, b_ih1, b_hh1,
                                       w_ih2, w_hh2, b_ih2, b_hh2,
                                       fc1_w, fc1_b, fc2_w, fc2_b,
                                       ln_g, ln_b, out);
}

// Round 16
// 462.605 us; speedup vs baseline: 1.3553x; 1.1028x over previous
//
#include <hip/hip_runtime.h>
#include <cstdint>
#include <cstddef>

#define T_STEPS 1024
#define NBLK    256   // 512 batch / 2 per block; 1 block per CU
#define LOG2E   1.4426950408889634f

typedef __attribute__((ext_vector_type(8))) _Float16 half8;
typedef __attribute__((ext_vector_type(4))) _Float16 half4;
typedef __attribute__((ext_vector_type(4))) float    f32x4;
typedef __attribute__((ext_vector_type(4))) int      i32x4;

static __device__ __forceinline__ float fexp2(float x) {
#if defined(__has_builtin) && __has_builtin(__builtin_amdgcn_exp2f)
  return __builtin_amdgcn_exp2f(x);
#else
  return __exp2f(x);
#endif
}
// pre-acts arrive PRE-SCALED by log2e
static __device__ __forceinline__ float sigm2(float a) {
  return __builtin_amdgcn_rcpf(1.0f + fexp2(-a));
}
static __device__ __forceinline__ float tanhg2(float a) {
  return 2.0f * __builtin_amdgcn_rcpf(1.0f + fexp2(-(a + a))) - 1.0f;
}
static __device__ __forceinline__ float tanhc(float c) {   // tanh(c), c unscaled
  return 1.0f - 2.0f * __builtin_amdgcn_rcpf(1.0f + fexp2(c * (2.0f * LOG2E)));
}

static __device__ __forceinline__ half8 load8s(const float* s, float sc) {
  float4 a = ((const float4*)s)[0];
  float4 b = ((const float4*)s)[1];
  half8 h;
  h[0] = (_Float16)(a.x * sc); h[1] = (_Float16)(a.y * sc);
  h[2] = (_Float16)(a.z * sc); h[3] = (_Float16)(a.w * sc);
  h[4] = (_Float16)(b.x * sc); h[5] = (_Float16)(b.y * sc);
  h[6] = (_Float16)(b.z * sc); h[7] = (_Float16)(b.w * sc);
  return h;
}
static __device__ __forceinline__ half4 cvt4(float4 v) {
  half4 h; h[0] = (_Float16)v.x; h[1] = (_Float16)v.y; h[2] = (_Float16)v.z; h[3] = (_Float16)v.w;
  return h;
}
// quantize 16 contiguous floats with scale s -> 16 i8 packed in 4 dwords
static __device__ __forceinline__ i32x4 quant16(const float* src, float s) {
  union { i32x4 v; signed char b[16]; } u;
  #pragma unroll
  for (int j = 0; j < 16; ++j) u.b[j] = (signed char)__float2int_rn(src[j] * s);
  return u.v;
}

// lgkm-only workgroup barrier (R8-verified): global loads float across it.
static __device__ __forceinline__ void barrier_lds() {
  __asm__ volatile("s_waitcnt lgkmcnt(0)\n\ts_barrier" ::: "memory");
}

// R16 = R15 (verified best: 510/478 us) + i8 h-path:
//  h1/h2 stored in LDS as i8 (|h|<1 strictly -> abs quant err 1/254). All
//  h-ksteps use v_mfma_i32_16x16x64_i8 — K=64 covers a whole h vector in ONE
//  instruction. Weights quantized per-ROW (s_r = 127/rowmax; legal since each
//  row's i32 lands in the act lane that owns the row; L2 shares one scale
//  across w_ih2/w_hh2 rows so both ksteps accumulate in one i32 acc).
//  x-kstep stays f16 MFMA (unbounded range), carrying the bias C-init.
//  MFMA/wave: L1 4 f16 + 4 i8 (was 12 f16); L2 8 i8 (was 16 f16).
//  Per-SIMD matrix-pipe floor: 543 -> ~320 cyc. L2 ds_reads halve.
// Act combine: L1 gate = accf(x+bias) + fs1*float(acci); L2 gate = bias +
//  fs2*float(acci); fs = rowmax*LOG2E/127^2. All else identical to R15
//  (skew-2 L2, zero-wait phase top via pre-read frags, lgkm-only barrier,
//  x bulk-prefetch on L1 waves, loop unrolled x2).
// MFMA layouts (m89/m120-verified; i8 A/B: k = quad*16 + bytelane, same
// K-contiguous pattern; C/D layout dtype-independent per m121-128).
__global__ __launch_bounds__(512, 2) void lstm_fused(
    const float* __restrict__ x,
    const float* __restrict__ w_ih1, const float* __restrict__ w_hh1,
    const float* __restrict__ b_ih1, const float* __restrict__ b_hh1,
    const float* __restrict__ w_ih2, const float* __restrict__ w_hh2,
    const float* __restrict__ b_ih2, const float* __restrict__ b_hh2,
    const float* __restrict__ fc1_w, const float* __restrict__ fc1_b,
    const float* __restrict__ fc2_w, const float* __restrict__ fc2_b,
    const float* __restrict__ ln_g, const float* __restrict__ ln_b,
    float* __restrict__ out)
{
  // i8 h-state: [buf][layer][batch][64] (batch stride 64B: banks 0-15/16-31)
  __shared__ __align__(16) signed char hs8[2][2][2][64];   // 512 B
  __shared__ __align__(16) _Float16 xbig[2][16][2][32];    // 4 KB (f16 x window)
  __shared__ __align__(16) float hfin[2][64];
  __shared__ __align__(16) float y1s[2][128];
  __shared__ __align__(16) float y2s[2][128];
  __shared__ float redmu[2], redrs[2];

  const int t   = threadIdx.x;
  const int b   = blockIdx.x;
  const int l   = t & 63;
  const int w   = t >> 6;       // wave 0..7
  const int ly  = w >> 2;       // 0=L1, 1=L2
  const int wq  = w & 3;        // unit group
  const int col = l & 15;
  const int q   = l >> 4;       // quad
  const int bm  = ((l & 15) >> 2) & 1;  // batch whose A-row this lane serves

  // ---- init: zero h-state (512 bytes) ----
  if (t < 512) ((signed char*)hs8)[t] = 0;

  // ---- init: preload x[0..16) into xbig buf0 ----
  if (t < 256) {
    const int b0 = t >> 7, r0 = t & 127, tr0 = r0 >> 3, ii0 = r0 & 7;
    const float4 v = *(const float4*)(x + ((size_t)(2 * b + b0) * T_STEPS + tr0) * 32 + ii0 * 4);
    *(half4*)((char*)xbig + tr0 * 128 + b0 * 64 + ii0 * 8) = cvt4(v);
  }

  // ---- stationary weights ----
  // L1: wbx = f16 w_ih1 (log2e-scaled); wqa = i8 w_hh1 (per-row scale).
  // L2: wqa = i8 w_ih2, wqb = i8 w_hh2 (shared per-row scale over both).
  half8 wbx[4];
  i32x4 wqa[4], wqb[4];
  float fs[4];    // rowmax * LOG2E / 127^2
  {
    #pragma unroll
    for (int tt = 0; tt < 4; ++tt) {
      const int r = tt * 64 + wq * 16 + col;
      if (ly == 0) {
        wbx[tt] = load8s(w_ih1 + r * 32 + q * 8, LOG2E);
        const float* s1 = w_hh1 + r * 64 + q * 16;
        float m = 0.0f;
        #pragma unroll
        for (int j = 0; j < 16; ++j) m = fmaxf(m, fabsf(s1[j]));
        m = fmaxf(m, __shfl_xor(m, 16, 64));
        m = fmaxf(m, __shfl_xor(m, 32, 64));
        const float s = 127.0f / m;
        wqa[tt] = quant16(s1, s);
        wqb[tt] = wqa[tt];                       // unused
        fs[tt] = m * (LOG2E / 16129.0f);
      } else {
        const float* s1 = w_ih2 + r * 64 + q * 16;
        const float* s2 = w_hh2 + r * 64 + q * 16;
        float m = 0.0f;
        #pragma unroll
        for (int j = 0; j < 16; ++j) m = fmaxf(m, fmaxf(fabsf(s1[j]), fabsf(s2[j])));
        m = fmaxf(m, __shfl_xor(m, 16, 64));
        m = fmaxf(m, __shfl_xor(m, 32, 64));
        const float s = 127.0f / m;
        wqa[tt] = quant16(s1, s);
        wqb[tt] = quant16(s2, s);
        fs[tt] = m * (LOG2E / 16129.0f);
      }
    }
  }

  // ---- per-tile bias (x LOG2E). L1: folded into f16 C-init; L2: act-time add.
  float bia[4];
  f32x4 biav[4];   // persistent C-init quads (L1)
  {
    const float* bi_ = ly ? b_ih2 : b_ih1;
    const float* bh_ = ly ? b_hh2 : b_hh1;
    #pragma unroll
    for (int tt = 0; tt < 4; ++tt) {
      const int r = tt * 64 + wq * 16 + col;
      bia[tt] = (bi_[r] + bh_[r]) * LOG2E;
      biav[tt] = (f32x4){bia[tt], bia[tt], bia[tt], bia[tt]};
    }
  }
  // act-lane mapping (lanes 0-31): unit u, batch = l>>4
  const int u   = wq * 16 + col;
  const int abm = l >> 4;
  const int hwofs = ly * 128 + abm * 64 + u;   // byte offset (+ buf*256)

  // ---- x-prefetch lanes: waves 0-3 ONLY, lanes 32-63 ----
  const bool isx = (w < 4) && (l >= 32);
  const int g   = w * 32 + (l - 32);      // 0..127
  const int xtr = g >> 3;
  const int xii = g & 7;
  const float* xsrc0 = x + ((size_t)(2 * b + 0) * T_STEPS) * 32 + xii * 4;
  const float* xsrc1 = x + ((size_t)(2 * b + 1) * T_STEPS) * 32 + xii * 4;

  const char* h8base = (const char*)hs8  + bm * 64 + q * 16;  // + buf*256 + layer*128
  const char* xwbase = (const char*)xbig + bm * 64 + q * 16;  // + buf*2048 + slot*128

  __syncthreads();

  // loop-carried pre-read fragments
  half8 xf;        // L1: x-frag consumed at next phase-top
  i32x4 h1f;       // L2: h1 i8-frag consumed at next phase-top
  if (ly == 0) xf = *(const half8*)xwbase;   // x_0

  float4 xv0 = make_float4(0.f, 0.f, 0.f, 0.f);
  float4 xv1 = make_float4(0.f, 0.f, 0.f, 0.f);
  float c = 0.0f;
  const i32x4 zi = (i32x4){0, 0, 0, 0};

  // phase body: h-writes -> buf WR8, reads -> buf RD8 (byte offsets, stride 256)
  auto phase = [&](int p, int RD8, int WR8) {
    if (isx && (p & 15) == 0 && (p + 16 + xtr) < T_STEPS) {
      xv0 = *(const float4*)(xsrc0 + (size_t)(p + 16 + xtr) * 32);
      xv1 = *(const float4*)(xsrc1 + (size_t)(p + 16 + xtr) * 32);
    }

    if (ly == 0) {
      // ---- L1, step t=p ----
      if (p < T_STEPS) {
        // TOP: f16 x-MFMAs from reg-held frag (no wait), C = bias
        f32x4 accf[4];
        #pragma unroll
        for (int tt = 0; tt < 4; ++tt)
          accf[tt] = __builtin_amdgcn_mfma_f32_16x16x32_f16(xf, wbx[tt], biav[tt], 0, 0, 0);
        // issue ds_reads: h1_{p-1} i8-frag (K=64 in one frag) + next x-frag
        const i32x4 a1 = *(const i32x4*)(h8base + RD8);        // layer0
        if (p + 1 < T_STEPS) {
          const int pn = p + 1;
          xf = *(const half8*)(xwbase + ((pn >> 4) & 1) * 2048 + (pn & 15) * 128);
        }
        // h1 kstep: ONE i8 MFMA per tile
        i32x4 acci[4];
        #pragma unroll
        for (int tt = 0; tt < 4; ++tt)
          acci[tt] = __builtin_amdgcn_mfma_i32_16x16x64_i8(a1, wqa[tt], zi, 0, 0, 0);
        if (l < 32) {
          const float gi = sigm2 (accf[0][0] + fs[0] * (float)acci[0][0]);
          const float gf = sigm2 (accf[1][0] + fs[1] * (float)acci[1][0]);
          const float gg = tanhg2(accf[2][0] + fs[2] * (float)acci[2][0]);
          const float go = sigm2 (accf[3][0] + fs[3] * (float)acci[3][0]);
          c = gf * c + gi * gg;
          const float hv = go * tanhc(c);
          ((signed char*)hs8)[WR8 + hwofs] = (signed char)__float2int_rn(hv * 127.0f);
        }
      }
      if (isx && (p & 15) == 8 && (p + 8 + xtr) < T_STEPS) {
        const int bb2 = (((p >> 4) + 1) & 1) * 2048 + xtr * 128 + xii * 8;
        *(half4*)((char*)xbig + bb2)      = cvt4(xv0);
        *(half4*)((char*)xbig + bb2 + 64) = cvt4(xv1);
      }
    } else {
      // ---- L2, finalize step t=p-2 ----
      i32x4 accq[4];
      if (p >= 2 && p <= T_STEPS + 1) {
        // TOP: h1-kstep i8 MFMAs from reg-held frag (read last phase)
        #pragma unroll
        for (int tt = 0; tt < 4; ++tt)
          accq[tt] = __builtin_amdgcn_mfma_i32_16x16x64_i8(h1f, wqa[tt], zi, 0, 0, 0);
      }
      // issue ds_reads: h2_{p-3} (finalize) + h1_{p-1} (next phase-top)
      i32x4 a2;
      if (p >= 2 && p <= T_STEPS + 1)
        a2 = *(const i32x4*)(h8base + RD8 + 128);              // layer1
      if (p >= 1 && p <= T_STEPS)
        h1f = *(const i32x4*)(h8base + RD8);                   // layer0
      if (p >= 2 && p <= T_STEPS + 1) {
        i32x4 acci[4];
        #pragma unroll
        for (int tt = 0; tt < 4; ++tt)
          acci[tt] = __builtin_amdgcn_mfma_i32_16x16x64_i8(a2, wqb[tt], accq[tt], 0, 0, 0);
        if (l < 32) {
          const float gi = sigm2 (bia[0] + fs[0] * (float)acci[0][0]);
          const float gf = sigm2 (bia[1] + fs[1] * (float)acci[1][0]);
          const float gg = tanhg2(bia[2] + fs[2] * (float)acci[2][0]);
          const float go = sigm2 (bia[3] + fs[3] * (float)acci[3][0]);
          c = gf * c + gi * gg;
          const float hv = go * tanhc(c);
          ((signed char*)hs8)[WR8 + hwofs] = (signed char)__float2int_rn(hv * 127.0f);
          if (p == T_STEPS + 1) hfin[abm][u] = hv;   // h2_{T-1} in f32
        }
      }
    }
  };

  // phases 0..T_STEPS+1 (L2 skew 2); even: read buf1/write buf0, odd: reverse
  for (int p2 = 0; p2 <= T_STEPS; p2 += 2) {
    phase(p2, 256, 0);
    barrier_lds();
    phase(p2 + 1, 0, 256);
    barrier_lds();
  }

  __syncthreads();   // full drain before epilogue

  // ---- head: y = LN(relu(hT@fc1^T+b1)@fc2^T+b2), 2 batch rows ----
  if (t < 256) {
    const int bi = t >> 7, j = t & 127;
    float a = fc1_b[j];
    const float4* w4 = (const float4*)(fc1_w + j * 64);
    const float4* h4 = (const float4*)hfin[bi];
    #pragma unroll
    for (int qq = 0; qq < 16; ++qq) {
      float4 wv = w4[qq]; float4 hv = h4[qq];
      a += wv.x * hv.x + wv.y * hv.y + wv.z * hv.z + wv.w * hv.w;
    }
    y1s[bi][j] = fmaxf(a, 0.0f);
  }
  __syncthreads();
  if (t < 256) {
    const int bi = t >> 7, j = t & 127;
    float a = fc2_b[j];
    const float4* w4 = (const float4*)(fc2_w + j * 128);
    const float4* y4 = (const float4*)y1s[bi];
    #pragma unroll
    for (int qq = 0; qq < 32; ++qq) {
      float4 wv = w4[qq]; float4 yv = y4[qq];
      a += wv.x * yv.x + wv.y * yv.y + wv.z * yv.z + wv.w * yv.w;
    }
    y2s[bi][j] = a;
  }
  __syncthreads();
  if (t < 128) {
    const int bi = t >> 6, jj = t & 63;
    float s  = y2s[bi][jj] + y2s[bi][64 + jj];
    float qs = y2s[bi][jj] * y2s[bi][jj] + y2s[bi][64 + jj] * y2s[bi][64 + jj];
    #pragma unroll
    for (int off = 32; off > 0; off >>= 1) {
      s  += __shfl_down(s, off, 64);
      qs += __shfl_down(qs, off, 64);
    }
    if (jj == 0) {
      const float mu  = s * (1.0f / 128.0f);
      const float var = qs * (1.0f / 128.0f) - mu * mu;
      redmu[bi] = mu;
      redrs[bi] = rsqrtf(var + 1e-5f);
    }
  }
  __syncthreads();
  if (t < 256) {
    const int bi = t >> 7, j = t & 127;
    out[(size_t)(2 * b + bi) * 128 + j] =
        (y2s[bi][j] - redmu[bi]) * redrs[bi] * ln_g[j] + ln_b[j];
  }
}

extern "C" void kernel_launch(void* const* d_in, const int* in_sizes, int n_in,
                              void* d_out, int out_size, void* d_ws, size_t ws_size,
                              hipStream_t stream) {
  const float* x     = (const float*)d_in[0];
  const float* w_ih1 = (const float*)d_in[1];
  const float* w_hh1 = (const float*)d_in[2];
  const float* b_ih1 = (const float*)d_in[3];
  const float* b_hh1 = (const float*)d_in[4];
  const float* w_ih2 = (const float*)d_in[5];
  const float* w_hh2 = (const float*)d_in[6];
  const float* b_ih2 = (const float*)d_in[7];
  const float* b_hh2 = (const float*)d_in[8];
  const float* fc1_w = (const float*)d_in[9];
  const float* fc1_b = (const float*)d_in[10];
  const float* fc2_w = (const float*)d_in[11];
  const float* fc2_b = (const float*)d_in[12];
  const float* ln_g  = (const float*)d_in[13];
  const float* ln_b  = (const float*)d_in[14];
  float* out = (float*)d_out;

  lstm_fused<<<NBLK, 512, 0, stream>>>(x, w_ih1, w_hh1, b_ih1, b_hh1,
                                       w_ih2, w_hh2, b_ih2, b_hh2,
                                       fc1_w, fc1_b, fc2_w, fc2_b,
                                       ln_g, ln_b, out);
}